// Round 8
// baseline (202.021 us; speedup 1.0000x reference)
//
#include <hip/hip_runtime.h>
#include <hip/hip_bf16.h>

// PointNet2 FP: 3-NN interp + concat + MLP(384->256->128) via bf16 MFMA
#define BB 2
#define NN 16384
#define MM 4096
#define C1 128
#define C2 256
#define CIN 384
#define H1 256
#define H2 128
#define PT 16          // points per block in fused MLP kernel
#define XROW 392       // 384 + 8 pad (row = 784 B)

typedef __attribute__((ext_vector_type(8))) short bf16x8;
typedef __attribute__((ext_vector_type(4))) float f32x4;
typedef __attribute__((ext_vector_type(2))) float f32x2;
typedef __attribute__((ext_vector_type(8))) float f32x8;

__device__ __forceinline__ short f32_to_bf16(float x) {
    unsigned u = __float_as_uint(x);
    u += 0x7fffu + ((u >> 16) & 1u);   // RNE
    return (short)(u >> 16);
}
__device__ __forceinline__ float bf16_to_f32(unsigned short u) {
    union { unsigned u; float f; } c; c.u = ((unsigned)u) << 16; return c.f;
}
__device__ __forceinline__ unsigned pack_bf16x2(float a, float b) {
    __hip_bfloat162 h = __float22bfloat162_rn(make_float2(a, b));
    union { __hip_bfloat162 h; unsigned u; } cv;
    cv.h = h;
    return cv.u;
}

// ---------------- Kernel 1: pack known -> kpk8 (tiny) ----------------
// kpk layout per 2-candidate group g: [x0,x1,y0,y1,z0,z1,n0,n1] (32 B)
__global__ __launch_bounds__(1024) void kpk_prep_kernel(
    const float* __restrict__ known, float* __restrict__ kpk8)
{
    int i = blockIdx.x * 1024 + threadIdx.x;
    if (i < BB * MM) {
        float x = known[3 * i + 0], y = known[3 * i + 1], z = known[3 * i + 2];
        float n = fmaf(x, x, fmaf(y, y, z * z));
        int g = i >> 1, j = i & 1;
        float* base = kpk8 + (size_t)g * 8;
        base[0 + j] = x; base[2 + j] = y; base[4 + j] = z; base[6 + j] = n;
    }
}

// ------- Kernel 2: fused 3-NN (blocks 0..511) + transpose->bf16
//         (512..2559) + weight casts (2560..2655). Block = 1024 threads.
__global__ __launch_bounds__(1024) void knn_aux_kernel(
    const float* __restrict__ unknown,   // (B,N,3)
    const float* __restrict__ kpk8,      // packed groups
    int*   __restrict__ idx_out,         // (B,N,3)
    float* __restrict__ w_out,           // (B,N,3)
    const float* __restrict__ KF,        // (B,C2,M)
    unsigned short* __restrict__ KT16,   // (B,M,C2) bf16
    const float* __restrict__ W1, const float* __restrict__ W2,
    short* __restrict__ W1b, short* __restrict__ W2b)
{
    __shared__ float pdv[16][64][3];
    __shared__ float vf[64];
    __shared__ float msc[64][8];
    __shared__ int   mid[64][8];
    __shared__ int   cnt[64];
    __shared__ float tl[32][33];

    const int bx  = blockIdx.x;
    const int tid = threadIdx.x;

    if (bx < 512) {
        // ================= 3-NN: two-pass, packed-fp32 scores ============
        const int lane = tid & 63;
        const int wv   = __builtin_amdgcn_readfirstlane(tid >> 6);  // 0..15
        const int b    = bx >> 8;
        const int n    = (bx & 255) * 64 + lane;

        if (tid < 64) cnt[tid] = 0;

        const float ux = unknown[((size_t)b * NN + n) * 3 + 0];
        const float uy = unknown[((size_t)b * NN + n) * 3 + 1];
        const float uz = unknown[((size_t)b * NN + n) * 3 + 2];
        const f32x2 ax2 = {-2.f * ux, -2.f * ux};
        const f32x2 ay2 = {-2.f * uy, -2.f * uy};
        const f32x2 az2 = {-2.f * uz, -2.f * uz};
        const float un = fmaf(ux, ux, fmaf(uy, uy, uz * uz));

        const int gbase = wv * 128;
        const float* __restrict__ kp = kpk8 + ((size_t)b * (MM / 2) + gbase) * 8;

        // Pass A: values-only top-3, DUAL accumulators (break fmed3 chain)
        float va0 = 3e38f, va1 = 3e38f, va2 = 3e38f;
        float vb0 = 3e38f, vb1 = 3e38f, vb2 = 3e38f;
        #pragma unroll 4
        for (int g = 0; g < 128; ++g) {
            const f32x8 G = *(const f32x8*)(kp + (size_t)g * 8);   // uniform
            const f32x2 kx = __builtin_shufflevector(G, G, 0, 1);
            const f32x2 ky = __builtin_shufflevector(G, G, 2, 3);
            const f32x2 kz = __builtin_shufflevector(G, G, 4, 5);
            const f32x2 kn = __builtin_shufflevector(G, G, 6, 7);
            const f32x2 sc2 = __builtin_elementwise_fma(ax2, kx,
                              __builtin_elementwise_fma(ay2, ky,
                              __builtin_elementwise_fma(az2, kz, kn)));
            float sa = sc2.x;
            va2 = __builtin_amdgcn_fmed3f(va1, sa, va2);
            va1 = __builtin_amdgcn_fmed3f(va0, sa, va1);
            va0 = fminf(sa, va0);
            float sb = sc2.y;
            vb2 = __builtin_amdgcn_fmed3f(vb1, sb, vb2);
            vb1 = __builtin_amdgcn_fmed3f(vb0, sb, vb1);
            vb0 = fminf(sb, vb0);
        }
        // merge B triple into A triple (insert one value at a time)
        {
            float bv[3] = {vb0, vb1, vb2};
            #pragma unroll
            for (int k = 0; k < 3; ++k) {
                float d = bv[k];
                va2 = __builtin_amdgcn_fmed3f(va1, d, va2);
                va1 = __builtin_amdgcn_fmed3f(va0, d, va1);
                va0 = fminf(d, va0);
            }
        }
        pdv[wv][lane][0] = va0; pdv[wv][lane][1] = va1; pdv[wv][lane][2] = va2;
        __syncthreads();

        if (tid < 64) {
            float r0 = 3e38f, r1 = 3e38f, r2 = 3e38f;
            #pragma unroll
            for (int ww = 0; ww < 16; ++ww) {
                #pragma unroll
                for (int k = 0; k < 3; ++k) {
                    float d = pdv[ww][tid][k];
                    r2 = __builtin_amdgcn_fmed3f(r1, d, r2);
                    r1 = __builtin_amdgcn_fmed3f(r0, d, r1);
                    r0 = fminf(d, r0);
                }
            }
            vf[tid] = r2;
        }
        __syncthreads();

        // Pass B: index recovery — identical score arithmetic
        const float v2f = vf[lane];
        #pragma unroll 4
        for (int g = 0; g < 128; ++g) {
            const f32x8 G = *(const f32x8*)(kp + (size_t)g * 8);
            const f32x2 kx = __builtin_shufflevector(G, G, 0, 1);
            const f32x2 ky = __builtin_shufflevector(G, G, 2, 3);
            const f32x2 kz = __builtin_shufflevector(G, G, 4, 5);
            const f32x2 kn = __builtin_shufflevector(G, G, 6, 7);
            const f32x2 sc2 = __builtin_elementwise_fma(ax2, kx,
                              __builtin_elementwise_fma(ay2, ky,
                              __builtin_elementwise_fma(az2, kz, kn)));
            if (fminf(sc2.x, sc2.y) <= v2f) {
                if (sc2.x <= v2f) {
                    int c = atomicAdd(&cnt[lane], 1);
                    if (c < 8) { msc[lane][c] = sc2.x; mid[lane][c] = (gbase + g) * 2; }
                }
                if (sc2.y <= v2f) {
                    int c = atomicAdd(&cnt[lane], 1);
                    if (c < 8) { msc[lane][c] = sc2.y; mid[lane][c] = (gbase + g) * 2 + 1; }
                }
            }
        }
        __syncthreads();

        if (tid < 64) {
            const int c = cnt[tid] < 8 ? cnt[tid] : 8;
            float r0 = 3e38f, r1 = 3e38f, r2 = 3e38f;
            int   q0 = 0x7FFFFFFF, q1 = 0x7FFFFFFF, q2 = 0x7FFFFFFF;
            #pragma unroll
            for (int k = 0; k < 8; ++k) {
                float d = (k < c) ? msc[tid][k] : 3e38f;
                int   j = (k < c) ? mid[tid][k] : 0x7FFFFFFF;
                const bool lt0 = (d < r0) || (d == r0 && j < q0);
                const bool lt1 = (d < r1) || (d == r1 && j < q1);
                const bool lt2 = (d < r2) || (d == r2 && j < q2);
                float nr2 = lt1 ? r1 : (lt2 ? d : r2);
                int   nq2 = lt1 ? q1 : (lt2 ? j : q2);
                float nr1 = lt0 ? r0 : (lt1 ? d : r1);
                int   nq1 = lt0 ? q0 : (lt1 ? j : q1);
                float nr0 = lt0 ? d : r0;
                int   nq0 = lt0 ? j : q0;
                r0 = nr0; r1 = nr1; r2 = nr2; q0 = nq0; q1 = nq1; q2 = nq2;
            }
            float d0 = sqrtf(fmaxf(r0 + un, 0.f));
            float d1 = sqrtf(fmaxf(r1 + un, 0.f));
            float d2 = sqrtf(fmaxf(r2 + un, 0.f));
            float i0 = 1.f / (d0 + 1e-8f);
            float i1 = 1.f / (d1 + 1e-8f);
            float i2 = 1.f / (d2 + 1e-8f);
            float s  = i0 + i1 + i2;
            const size_t ob = ((size_t)(bx >> 8) * NN + n) * 3;
            idx_out[ob + 0] = q0; idx_out[ob + 1] = q1; idx_out[ob + 2] = q2;
            w_out[ob + 0] = i0 / s; w_out[ob + 1] = i1 / s; w_out[ob + 2] = i2 / s;
        }
    } else if (bx < 2560) {
        // ================= transpose KF (B,C2,M) -> KT16 (B,M,C2) bf16 ===
        const int t  = bx - 512;
        const int b  = t >> 10;
        const int c0 = ((t >> 7) & 7) * 32;
        const int m0 = (t & 127) * 32;
        {
            const int tx = tid & 31;
            const int ty = tid >> 5;            // 0..31
            tl[ty][tx] = KF[((size_t)b * C2 + c0 + ty) * MM + m0 + tx];
            __syncthreads();
            KT16[((size_t)b * MM + m0 + ty) * C2 + c0 + tx] = (unsigned short)f32_to_bf16(tl[tx][ty]);
        }
    } else {
        // ================= weight casts ==================================
        int i = (bx - 2560) * 1024 + tid;
        if (i < H1 * CIN) W1b[i] = f32_to_bf16(W1[i]);
        if (i < H2 * H1)  W2b[i] = f32_to_bf16(W2[i]);
    }
}

// ---------------- Kernel 3: fused gather-interp + 2-layer MFMA MLP -------
// grid 2048 (= B * N/PT), block 256 (4 waves). PT=16: LDS ~13 KB ->
// ~7 blocks/CU resident (28 waves/CU) to hide gather latency.
// Single aliased LDS buffer XH holds X then H; GEMM1 acc in registers.
__global__ __launch_bounds__(256, 7) void fp_mlp_mfma_kernel(
    const float* __restrict__ unknow_feats,   // (B,C1,N)
    const unsigned short* __restrict__ KT16,  // (B,M,C2) bf16
    const short* __restrict__ W1b,            // (H1,CIN) bf16
    const float* __restrict__ b1,
    const short* __restrict__ W2b,            // (H2,H1) bf16
    const float* __restrict__ b2,
    const int*   __restrict__ idx,            // (B,N,3)
    const float* __restrict__ wgt,            // (B,N,3)
    float* __restrict__ out)                  // (B,H2,N)
{
    __shared__ short XH[PT][XROW];
    __shared__ int   Is[PT * 3];
    __shared__ float Ws[PT * 3];

    const int tid  = threadIdx.x;
    const int blocks_per_b = NN / PT;             // 1024
    const int b    = blockIdx.x / blocks_per_b;
    const int n0   = (blockIdx.x % blocks_per_b) * PT;
    const int w    = tid >> 6;                    // wave 0..3
    const int lane = tid & 63;
    const int lr   = lane & 15;
    const int lq   = lane >> 4;

    if (tid < PT * 3) {
        const size_t base = ((size_t)b * NN + n0) * 3;
        Is[tid] = idx[base + tid];
        Ws[tid] = wgt[base + tid];
    }
    __syncthreads();

    // ---- X-build: wave = 1 point, lane = 4 channels; issue all gathers ----
    {
        const unsigned short* KTb = KT16 + (size_t)b * MM * C2;
        const int c4 = (lane << 2);               // 0..252
        ushort4 g[4][3];
        #pragma unroll
        for (int i = 0; i < 4; ++i) {
            const int p = i * 4 + w;
            g[i][0] = *(const ushort4*)(KTb + (size_t)Is[3 * p + 0] * C2 + c4);
            g[i][1] = *(const ushort4*)(KTb + (size_t)Is[3 * p + 1] * C2 + c4);
            g[i][2] = *(const ushort4*)(KTb + (size_t)Is[3 * p + 2] * C2 + c4);
        }
        #pragma unroll
        for (int i = 0; i < 4; ++i) {
            const int p = i * 4 + w;
            const float w0 = Ws[3 * p + 0], w1 = Ws[3 * p + 1], w2 = Ws[3 * p + 2];
            float vx = fmaf(w0, bf16_to_f32(g[i][0].x), fmaf(w1, bf16_to_f32(g[i][1].x), w2 * bf16_to_f32(g[i][2].x)));
            float vy = fmaf(w0, bf16_to_f32(g[i][0].y), fmaf(w1, bf16_to_f32(g[i][1].y), w2 * bf16_to_f32(g[i][2].y)));
            float vz = fmaf(w0, bf16_to_f32(g[i][0].z), fmaf(w1, bf16_to_f32(g[i][1].z), w2 * bf16_to_f32(g[i][2].z)));
            float vw = fmaf(w0, bf16_to_f32(g[i][0].w), fmaf(w1, bf16_to_f32(g[i][1].w), w2 * bf16_to_f32(g[i][2].w)));
            uint2 pk;
            pk.x = pack_bf16x2(vx, vy);
            pk.y = pack_bf16x2(vz, vw);
            *(uint2*)&XH[p][c4] = pk;
        }
        const float* UFb = unknow_feats + (size_t)b * C1 * NN + n0;
        #pragma unroll
        for (int i = 0; i < 2; ++i) {
            int e  = i * 256 + tid;
            int cc = e >> 2;                      // 0..127
            int nq = (e & 3) << 2;                // 0,4,8,12
            const float4 f = *(const float4*)(UFb + (size_t)cc * NN + nq);
            XH[nq + 0][C2 + cc] = f32_to_bf16(f.x);
            XH[nq + 1][C2 + cc] = f32_to_bf16(f.y);
            XH[nq + 2][C2 + cc] = f32_to_bf16(f.z);
            XH[nq + 3][C2 + cc] = f32_to_bf16(f.w);
        }
    }
    __syncthreads();

    // GEMM1: acc = W1 * X  (acc stays in registers across the alias barrier)
    f32x4 acc[4];
    #pragma unroll
    for (int t = 0; t < 4; ++t) acc[t] = (f32x4){0.f, 0.f, 0.f, 0.f};

    #pragma unroll 4
    for (int k0 = 0; k0 < CIN; k0 += 32) {
        bf16x8 a[4], x;
        #pragma unroll
        for (int t = 0; t < 4; ++t)
            a[t] = *(const bf16x8*)(W1b + (size_t)(w * 64 + t * 16 + lr) * CIN + k0 + lq * 8);
        x = *(bf16x8*)&XH[lr][k0 + lq * 8];
        #pragma unroll
        for (int t = 0; t < 4; ++t)
            acc[t] = __builtin_amdgcn_mfma_f32_16x16x32_bf16(a[t], x, acc[t], 0, 0, 0);
    }
    __syncthreads();   // all X reads done — safe to overwrite XH with H

    // H = ReLU(acc + b1) -> XH (cols 0..255)
    #pragma unroll
    for (int t = 0; t < 4; ++t) {
        const int obase = w * 64 + t * 16 + lq * 4;
        float bb0 = b1[obase + 0], bb1 = b1[obase + 1],
              bb2 = b1[obase + 2], bb3 = b1[obase + 3];
        uint2 pk;
        pk.x = pack_bf16x2(fmaxf(acc[t].x + bb0, 0.f),
                           fmaxf(acc[t].y + bb1, 0.f));
        pk.y = pack_bf16x2(fmaxf(acc[t].z + bb2, 0.f),
                           fmaxf(acc[t].w + bb3, 0.f));
        *(uint2*)&XH[lr][obase] = pk;
    }
    __syncthreads();

    // GEMM2: Out[128 x PT] = ReLU(W2 * H + b2)
    {
        f32x4 acc2[2];
        #pragma unroll
        for (int t = 0; t < 2; ++t) acc2[t] = (f32x4){0.f, 0.f, 0.f, 0.f};

        #pragma unroll 4
        for (int k0 = 0; k0 < H1; k0 += 32) {
            bf16x8 a[2], h;
            #pragma unroll
            for (int t = 0; t < 2; ++t)
                a[t] = *(const bf16x8*)(W2b + (size_t)(w * 32 + t * 16 + lr) * H1 + k0 + lq * 8);
            h = *(bf16x8*)&XH[lr][k0 + lq * 8];
            #pragma unroll
            for (int t = 0; t < 2; ++t)
                acc2[t] = __builtin_amdgcn_mfma_f32_16x16x32_bf16(a[t], h, acc2[t], 0, 0, 0);
        }
        #pragma unroll
        for (int t = 0; t < 2; ++t) {
            const int obase = w * 32 + t * 16 + lq * 4;
            const int n = n0 + lr;
            #pragma unroll
            for (int r = 0; r < 4; ++r) {
                const int o = obase + r;
                out[((size_t)b * H2 + o) * NN + n] =
                    fmaxf(((const float*)&acc2[t])[r] + b2[o], 0.f);
            }
        }
    }
}

extern "C" void kernel_launch(void* const* d_in, const int* in_sizes, int n_in,
                              void* d_out, int out_size, void* d_ws, size_t ws_size,
                              hipStream_t stream) {
    const float* unknown      = (const float*)d_in[0];
    const float* known        = (const float*)d_in[1];
    const float* unknow_feats = (const float*)d_in[2];
    const float* known_feats  = (const float*)d_in[3];
    const float* W1           = (const float*)d_in[4];
    const float* b1           = (const float*)d_in[5];
    const float* W2           = (const float*)d_in[6];
    const float* b2           = (const float*)d_in[7];
    float* out = (float*)d_out;

    char* ws = (char*)d_ws;
    int*            idx  = (int*)(ws);                      // 393216 B
    float*          wgt  = (float*)(ws + 393216);           // 393216 B
    short*          W1b  = (short*)(ws + 786432);           // 196608 B
    short*          W2b  = (short*)(ws + 983040);           // 65536 B
    float*          kpk8 = (float*)(ws + 1048576);          // 131072 B
    unsigned short* KT16 = (unsigned short*)(ws + 1179648); // 4194304 B

    kpk_prep_kernel<<<8, 1024, 0, stream>>>(known, kpk8);

    knn_aux_kernel<<<2656, 1024, 0, stream>>>(
        unknown, kpk8, idx, wgt, known_feats, KT16, W1, W2, W1b, W2b);

    fp_mlp_mfma_kernel<<<BB * (NN / PT), 256, 0, stream>>>(
        unknow_feats, KT16, W1b, b1, W2b, b2, idx, wgt, out);
}

// Round 9
// 167.856 us; speedup vs baseline: 1.2035x; 1.2035x over previous
//
#include <hip/hip_runtime.h>
#include <hip/hip_bf16.h>

// PointNet2 FP: 3-NN interp + concat + MLP(384->256->128) via bf16 MFMA
#define BB 2
#define NN 16384
#define MM 4096
#define C1 128
#define C2 256
#define CIN 384
#define H1 256
#define H2 128
#define PT 32          // points per tile in fused MLP kernel
#define TILES 2        // tiles per block (software pipeline depth)
#define XROW 392       // 384 + 8 pad (row = 784 B)

typedef __attribute__((ext_vector_type(8))) short bf16x8;
typedef __attribute__((ext_vector_type(4))) float f32x4;
typedef __attribute__((ext_vector_type(2))) float f32x2;
typedef __attribute__((ext_vector_type(8))) float f32x8;

__device__ __forceinline__ short f32_to_bf16(float x) {
    unsigned u = __float_as_uint(x);
    u += 0x7fffu + ((u >> 16) & 1u);   // RNE
    return (short)(u >> 16);
}
__device__ __forceinline__ float bf16_to_f32(unsigned short u) {
    union { unsigned u; float f; } c; c.u = ((unsigned)u) << 16; return c.f;
}
__device__ __forceinline__ unsigned pack_bf16x2(float a, float b) {
    __hip_bfloat162 h = __float22bfloat162_rn(make_float2(a, b));
    union { __hip_bfloat162 h; unsigned u; } cv;
    cv.h = h;
    return cv.u;
}

// ---------------- Kernel 1: pack known -> kpk8 (tiny) ----------------
__global__ __launch_bounds__(1024) void kpk_prep_kernel(
    const float* __restrict__ known, float* __restrict__ kpk8)
{
    int i = blockIdx.x * 1024 + threadIdx.x;
    if (i < BB * MM) {
        float x = known[3 * i + 0], y = known[3 * i + 1], z = known[3 * i + 2];
        float n = fmaf(x, x, fmaf(y, y, z * z));
        int g = i >> 1, j = i & 1;
        float* base = kpk8 + (size_t)g * 8;
        base[0 + j] = x; base[2 + j] = y; base[4 + j] = z; base[6 + j] = n;
    }
}

// ------- Kernel 2: fused 3-NN (blocks 0..511) + transpose->bf16
//         (512..2559) + weight casts (2560..2655). Block = 1024 threads.
__global__ __launch_bounds__(1024) void knn_aux_kernel(
    const float* __restrict__ unknown,   // (B,N,3)
    const float* __restrict__ kpk8,      // packed groups
    int*   __restrict__ idx_out,         // (B,N,3)
    float* __restrict__ w_out,           // (B,N,3)
    const float* __restrict__ KF,        // (B,C2,M)
    unsigned short* __restrict__ KT16,   // (B,M,C2) bf16
    const float* __restrict__ W1, const float* __restrict__ W2,
    short* __restrict__ W1b, short* __restrict__ W2b)
{
    __shared__ float pdv[16][64][3];
    __shared__ float vf[64];
    __shared__ float msc[64][8];
    __shared__ int   mid[64][8];
    __shared__ int   cnt[64];
    __shared__ float tl[32][33];

    const int bx  = blockIdx.x;
    const int tid = threadIdx.x;

    if (bx < 512) {
        const int lane = tid & 63;
        const int wv   = __builtin_amdgcn_readfirstlane(tid >> 6);  // 0..15
        const int b    = bx >> 8;
        const int n    = (bx & 255) * 64 + lane;

        if (tid < 64) cnt[tid] = 0;

        const float ux = unknown[((size_t)b * NN + n) * 3 + 0];
        const float uy = unknown[((size_t)b * NN + n) * 3 + 1];
        const float uz = unknown[((size_t)b * NN + n) * 3 + 2];
        const f32x2 ax2 = {-2.f * ux, -2.f * ux};
        const f32x2 ay2 = {-2.f * uy, -2.f * uy};
        const f32x2 az2 = {-2.f * uz, -2.f * uz};
        const float un = fmaf(ux, ux, fmaf(uy, uy, uz * uz));

        const int gbase = wv * 128;
        const float* __restrict__ kp = kpk8 + ((size_t)b * (MM / 2) + gbase) * 8;

        // Pass A: values-only top-3, dual accumulators
        float va0 = 3e38f, va1 = 3e38f, va2 = 3e38f;
        float vb0 = 3e38f, vb1 = 3e38f, vb2 = 3e38f;
        #pragma unroll 4
        for (int g = 0; g < 128; ++g) {
            const f32x8 G = *(const f32x8*)(kp + (size_t)g * 8);   // uniform
            const f32x2 kx = __builtin_shufflevector(G, G, 0, 1);
            const f32x2 ky = __builtin_shufflevector(G, G, 2, 3);
            const f32x2 kz = __builtin_shufflevector(G, G, 4, 5);
            const f32x2 kn = __builtin_shufflevector(G, G, 6, 7);
            const f32x2 sc2 = __builtin_elementwise_fma(ax2, kx,
                              __builtin_elementwise_fma(ay2, ky,
                              __builtin_elementwise_fma(az2, kz, kn)));
            float sa = sc2.x;
            va2 = __builtin_amdgcn_fmed3f(va1, sa, va2);
            va1 = __builtin_amdgcn_fmed3f(va0, sa, va1);
            va0 = fminf(sa, va0);
            float sb = sc2.y;
            vb2 = __builtin_amdgcn_fmed3f(vb1, sb, vb2);
            vb1 = __builtin_amdgcn_fmed3f(vb0, sb, vb1);
            vb0 = fminf(sb, vb0);
        }
        {
            float bv[3] = {vb0, vb1, vb2};
            #pragma unroll
            for (int k = 0; k < 3; ++k) {
                float d = bv[k];
                va2 = __builtin_amdgcn_fmed3f(va1, d, va2);
                va1 = __builtin_amdgcn_fmed3f(va0, d, va1);
                va0 = fminf(d, va0);
            }
        }
        pdv[wv][lane][0] = va0; pdv[wv][lane][1] = va1; pdv[wv][lane][2] = va2;
        __syncthreads();

        if (tid < 64) {
            float r0 = 3e38f, r1 = 3e38f, r2 = 3e38f;
            #pragma unroll
            for (int ww = 0; ww < 16; ++ww) {
                #pragma unroll
                for (int k = 0; k < 3; ++k) {
                    float d = pdv[ww][tid][k];
                    r2 = __builtin_amdgcn_fmed3f(r1, d, r2);
                    r1 = __builtin_amdgcn_fmed3f(r0, d, r1);
                    r0 = fminf(d, r0);
                }
            }
            vf[tid] = r2;
        }
        __syncthreads();

        // Pass B: index recovery — identical score arithmetic
        const float v2f = vf[lane];
        #pragma unroll 4
        for (int g = 0; g < 128; ++g) {
            const f32x8 G = *(const f32x8*)(kp + (size_t)g * 8);
            const f32x2 kx = __builtin_shufflevector(G, G, 0, 1);
            const f32x2 ky = __builtin_shufflevector(G, G, 2, 3);
            const f32x2 kz = __builtin_shufflevector(G, G, 4, 5);
            const f32x2 kn = __builtin_shufflevector(G, G, 6, 7);
            const f32x2 sc2 = __builtin_elementwise_fma(ax2, kx,
                              __builtin_elementwise_fma(ay2, ky,
                              __builtin_elementwise_fma(az2, kz, kn)));
            if (fminf(sc2.x, sc2.y) <= v2f) {
                if (sc2.x <= v2f) {
                    int c = atomicAdd(&cnt[lane], 1);
                    if (c < 8) { msc[lane][c] = sc2.x; mid[lane][c] = (gbase + g) * 2; }
                }
                if (sc2.y <= v2f) {
                    int c = atomicAdd(&cnt[lane], 1);
                    if (c < 8) { msc[lane][c] = sc2.y; mid[lane][c] = (gbase + g) * 2 + 1; }
                }
            }
        }
        __syncthreads();

        if (tid < 64) {
            const int c = cnt[tid] < 8 ? cnt[tid] : 8;
            float r0 = 3e38f, r1 = 3e38f, r2 = 3e38f;
            int   q0 = 0x7FFFFFFF, q1 = 0x7FFFFFFF, q2 = 0x7FFFFFFF;
            #pragma unroll
            for (int k = 0; k < 8; ++k) {
                float d = (k < c) ? msc[tid][k] : 3e38f;
                int   j = (k < c) ? mid[tid][k] : 0x7FFFFFFF;
                const bool lt0 = (d < r0) || (d == r0 && j < q0);
                const bool lt1 = (d < r1) || (d == r1 && j < q1);
                const bool lt2 = (d < r2) || (d == r2 && j < q2);
                float nr2 = lt1 ? r1 : (lt2 ? d : r2);
                int   nq2 = lt1 ? q1 : (lt2 ? j : q2);
                float nr1 = lt0 ? r0 : (lt1 ? d : r1);
                int   nq1 = lt0 ? q0 : (lt1 ? j : q1);
                float nr0 = lt0 ? d : r0;
                int   nq0 = lt0 ? j : q0;
                r0 = nr0; r1 = nr1; r2 = nr2; q0 = nq0; q1 = nq1; q2 = nq2;
            }
            float d0 = sqrtf(fmaxf(r0 + un, 0.f));
            float d1 = sqrtf(fmaxf(r1 + un, 0.f));
            float d2 = sqrtf(fmaxf(r2 + un, 0.f));
            float i0 = 1.f / (d0 + 1e-8f);
            float i1 = 1.f / (d1 + 1e-8f);
            float i2 = 1.f / (d2 + 1e-8f);
            float s  = i0 + i1 + i2;
            const size_t ob = ((size_t)(bx >> 8) * NN + n) * 3;
            idx_out[ob + 0] = q0; idx_out[ob + 1] = q1; idx_out[ob + 2] = q2;
            w_out[ob + 0] = i0 / s; w_out[ob + 1] = i1 / s; w_out[ob + 2] = i2 / s;
        }
    } else if (bx < 2560) {
        // transpose KF (B,C2,M) -> KT16 (B,M,C2) bf16
        const int t  = bx - 512;
        const int b  = t >> 10;
        const int c0 = ((t >> 7) & 7) * 32;
        const int m0 = (t & 127) * 32;
        {
            const int tx = tid & 31;
            const int ty = tid >> 5;            // 0..31
            tl[ty][tx] = KF[((size_t)b * C2 + c0 + ty) * MM + m0 + tx];
            __syncthreads();
            KT16[((size_t)b * MM + m0 + ty) * C2 + c0 + tx] = (unsigned short)f32_to_bf16(tl[tx][ty]);
        }
    } else {
        int i = (bx - 2560) * 1024 + tid;
        if (i < H1 * CIN) W1b[i] = f32_to_bf16(W1[i]);
        if (i < H2 * H1)  W2b[i] = f32_to_bf16(W2[i]);
    }
}

// ---------------- Kernel 3: pipelined gather-interp + 2-layer MFMA MLP ----
// grid 512 (= B*N/(PT*TILES)), block 256 (4 waves). Each block processes
// TILES=2 consecutive 32-point tiles; tile t+1's scattered gathers are
// issued into registers before tile t's GEMMs, hiding gather latency
// behind MFMA work. Single aliased LDS buffer XH (X then H per tile).
__global__ __launch_bounds__(256) void fp_mlp_mfma_kernel(
    const float* __restrict__ unknow_feats,   // (B,C1,N)
    const unsigned short* __restrict__ KT16,  // (B,M,C2) bf16
    const short* __restrict__ W1b,            // (H1,CIN) bf16
    const float* __restrict__ b1,
    const short* __restrict__ W2b,            // (H2,H1) bf16
    const float* __restrict__ b2,
    const int*   __restrict__ idx,            // (B,N,3)
    const float* __restrict__ wgt,            // (B,N,3)
    float* __restrict__ out)                  // (B,H2,N)
{
    __shared__ short XH[PT][XROW];
    __shared__ int   Is[TILES][PT * 3];
    __shared__ float Ws[TILES][PT * 3];

    const int tid  = threadIdx.x;
    const int blk  = blockIdx.x;                  // 0..511
    const int b    = blk >> 8;
    const int t0   = (blk & 255) * TILES;         // tile base within batch
    const int w    = tid >> 6;                    // wave 0..3
    const int lane = tid & 63;
    const int lr   = lane & 15;
    const int lq   = lane >> 4;
    const int c4   = lane << 2;                   // 0..252

    // stage ALL tiles' idx/weights up front
    if (tid < TILES * PT * 3) {
        const int tt = tid / (PT * 3), e = tid % (PT * 3);
        const size_t base = ((size_t)b * NN + (size_t)(t0 + tt) * PT) * 3;
        Is[tt][e] = idx[base + e];
        Ws[tt][e] = wgt[base + e];
    }
    __syncthreads();

    const unsigned short* KTb = KT16 + (size_t)b * MM * C2;

    // ---- prologue: gather + build X for tile 0 ----
    ushort4 g[8][3];
    #pragma unroll
    for (int i = 0; i < 8; ++i) {
        const int p = i * 4 + w;
        g[i][0] = *(const ushort4*)(KTb + (size_t)Is[0][3 * p + 0] * C2 + c4);
        g[i][1] = *(const ushort4*)(KTb + (size_t)Is[0][3 * p + 1] * C2 + c4);
        g[i][2] = *(const ushort4*)(KTb + (size_t)Is[0][3 * p + 2] * C2 + c4);
    }
    {
        #pragma unroll
        for (int i = 0; i < 8; ++i) {
            const int p = i * 4 + w;
            const float w0 = Ws[0][3 * p + 0], w1 = Ws[0][3 * p + 1], w2 = Ws[0][3 * p + 2];
            float vx = fmaf(w0, bf16_to_f32(g[i][0].x), fmaf(w1, bf16_to_f32(g[i][1].x), w2 * bf16_to_f32(g[i][2].x)));
            float vy = fmaf(w0, bf16_to_f32(g[i][0].y), fmaf(w1, bf16_to_f32(g[i][1].y), w2 * bf16_to_f32(g[i][2].y)));
            float vz = fmaf(w0, bf16_to_f32(g[i][0].z), fmaf(w1, bf16_to_f32(g[i][1].z), w2 * bf16_to_f32(g[i][2].z)));
            float vw = fmaf(w0, bf16_to_f32(g[i][0].w), fmaf(w1, bf16_to_f32(g[i][1].w), w2 * bf16_to_f32(g[i][2].w)));
            uint2 pk;
            pk.x = pack_bf16x2(vx, vy);
            pk.y = pack_bf16x2(vz, vw);
            *(uint2*)&XH[p][c4] = pk;
        }
        const float* UFb = unknow_feats + (size_t)b * C1 * NN + (size_t)t0 * PT;
        #pragma unroll
        for (int i = 0; i < 4; ++i) {
            int e  = i * 256 + tid;
            int cc = e >> 3;                      // 0..127
            int nq = (e & 7) << 2;                // 0,4,..,28
            const float4 f = *(const float4*)(UFb + (size_t)cc * NN + nq);
            XH[nq + 0][C2 + cc] = f32_to_bf16(f.x);
            XH[nq + 1][C2 + cc] = f32_to_bf16(f.y);
            XH[nq + 2][C2 + cc] = f32_to_bf16(f.z);
            XH[nq + 3][C2 + cc] = f32_to_bf16(f.w);
        }
    }
    __syncthreads();

    for (int t = 0; t < TILES; ++t) {
        const int n0 = (t0 + t) * PT;

        // issue next tile's scattered gathers NOW — they complete during GEMMs
        if (t + 1 < TILES) {
            #pragma unroll
            for (int i = 0; i < 8; ++i) {
                const int p = i * 4 + w;
                g[i][0] = *(const ushort4*)(KTb + (size_t)Is[t + 1][3 * p + 0] * C2 + c4);
                g[i][1] = *(const ushort4*)(KTb + (size_t)Is[t + 1][3 * p + 1] * C2 + c4);
                g[i][2] = *(const ushort4*)(KTb + (size_t)Is[t + 1][3 * p + 2] * C2 + c4);
            }
        }

        // GEMM1: acc = W1 * X (registers carried across alias barrier)
        f32x4 acc[4][2];
        #pragma unroll
        for (int tt = 0; tt < 4; ++tt)
            #pragma unroll
            for (int p = 0; p < 2; ++p) acc[tt][p] = (f32x4){0.f, 0.f, 0.f, 0.f};

        #pragma unroll 4
        for (int k0 = 0; k0 < CIN; k0 += 32) {
            bf16x8 a[4], x[2];
            #pragma unroll
            for (int tt = 0; tt < 4; ++tt)
                a[tt] = *(const bf16x8*)(W1b + (size_t)(w * 64 + tt * 16 + lr) * CIN + k0 + lq * 8);
            #pragma unroll
            for (int p = 0; p < 2; ++p)
                x[p] = *(bf16x8*)&XH[p * 16 + lr][k0 + lq * 8];
            #pragma unroll
            for (int tt = 0; tt < 4; ++tt)
                #pragma unroll
                for (int p = 0; p < 2; ++p)
                    acc[tt][p] = __builtin_amdgcn_mfma_f32_16x16x32_bf16(a[tt], x[p], acc[tt][p], 0, 0, 0);
        }
        __syncthreads();   // X reads done — safe to overwrite XH with H

        #pragma unroll
        for (int tt = 0; tt < 4; ++tt) {
            const int obase = w * 64 + tt * 16 + lq * 4;
            float bb0 = b1[obase + 0], bb1 = b1[obase + 1],
                  bb2 = b1[obase + 2], bb3 = b1[obase + 3];
            #pragma unroll
            for (int p = 0; p < 2; ++p) {
                uint2 pk;
                pk.x = pack_bf16x2(fmaxf(acc[tt][p].x + bb0, 0.f),
                                   fmaxf(acc[tt][p].y + bb1, 0.f));
                pk.y = pack_bf16x2(fmaxf(acc[tt][p].z + bb2, 0.f),
                                   fmaxf(acc[tt][p].w + bb3, 0.f));
                *(uint2*)&XH[p * 16 + lr][obase] = pk;
            }
        }
        __syncthreads();

        // GEMM2: Out = ReLU(W2 * H + b2)
        {
            f32x4 acc2[2][2];
            #pragma unroll
            for (int tt = 0; tt < 2; ++tt)
                #pragma unroll
                for (int p = 0; p < 2; ++p) acc2[tt][p] = (f32x4){0.f, 0.f, 0.f, 0.f};

            #pragma unroll 4
            for (int k0 = 0; k0 < H1; k0 += 32) {
                bf16x8 a[2], h[2];
                #pragma unroll
                for (int tt = 0; tt < 2; ++tt)
                    a[tt] = *(const bf16x8*)(W2b + (size_t)(w * 32 + tt * 16 + lr) * H1 + k0 + lq * 8);
                #pragma unroll
                for (int p = 0; p < 2; ++p)
                    h[p] = *(bf16x8*)&XH[p * 16 + lr][k0 + lq * 8];
                #pragma unroll
                for (int tt = 0; tt < 2; ++tt)
                    #pragma unroll
                    for (int p = 0; p < 2; ++p)
                        acc2[tt][p] = __builtin_amdgcn_mfma_f32_16x16x32_bf16(a[tt], h[p], acc2[tt][p], 0, 0, 0);
            }
            #pragma unroll
            for (int tt = 0; tt < 2; ++tt) {
                const int obase = w * 32 + tt * 16 + lq * 4;
                #pragma unroll
                for (int p = 0; p < 2; ++p) {
                    const int n = n0 + p * 16 + lr;
                    #pragma unroll
                    for (int r = 0; r < 4; ++r) {
                        const int o = obase + r;
                        out[((size_t)b * H2 + o) * NN + n] =
                            fmaxf(((const float*)&acc2[tt][p])[r] + b2[o], 0.f);
                    }
                }
            }
        }
        __syncthreads();   // H reads done — XH free for next tile's X

        // build X for tile t+1 from the prefetched registers
        if (t + 1 < TILES) {
            #pragma unroll
            for (int i = 0; i < 8; ++i) {
                const int p = i * 4 + w;
                const float w0 = Ws[t + 1][3 * p + 0], w1 = Ws[t + 1][3 * p + 1], w2 = Ws[t + 1][3 * p + 2];
                float vx = fmaf(w0, bf16_to_f32(g[i][0].x), fmaf(w1, bf16_to_f32(g[i][1].x), w2 * bf16_to_f32(g[i][2].x)));
                float vy = fmaf(w0, bf16_to_f32(g[i][0].y), fmaf(w1, bf16_to_f32(g[i][1].y), w2 * bf16_to_f32(g[i][2].y)));
                float vz = fmaf(w0, bf16_to_f32(g[i][0].z), fmaf(w1, bf16_to_f32(g[i][1].z), w2 * bf16_to_f32(g[i][2].z)));
                float vw = fmaf(w0, bf16_to_f32(g[i][0].w), fmaf(w1, bf16_to_f32(g[i][1].w), w2 * bf16_to_f32(g[i][2].w)));
                uint2 pk;
                pk.x = pack_bf16x2(vx, vy);
                pk.y = pack_bf16x2(vz, vw);
                *(uint2*)&XH[p][c4] = pk;
            }
            const float* UFb = unknow_feats + (size_t)b * C1 * NN + (size_t)(t0 + t + 1) * PT;
            #pragma unroll
            for (int i = 0; i < 4; ++i) {
                int e  = i * 256 + tid;
                int cc = e >> 3;
                int nq = (e & 7) << 2;
                const float4 f = *(const float4*)(UFb + (size_t)cc * NN + nq);
                XH[nq + 0][C2 + cc] = f32_to_bf16(f.x);
                XH[nq + 1][C2 + cc] = f32_to_bf16(f.y);
                XH[nq + 2][C2 + cc] = f32_to_bf16(f.z);
                XH[nq + 3][C2 + cc] = f32_to_bf16(f.w);
            }
            __syncthreads();
        }
    }
}

extern "C" void kernel_launch(void* const* d_in, const int* in_sizes, int n_in,
                              void* d_out, int out_size, void* d_ws, size_t ws_size,
                              hipStream_t stream) {
    const float* unknown      = (const float*)d_in[0];
    const float* known        = (const float*)d_in[1];
    const float* unknow_feats = (const float*)d_in[2];
    const float* known_feats  = (const float*)d_in[3];
    const float* W1           = (const float*)d_in[4];
    const float* b1           = (const float*)d_in[5];
    const float* W2           = (const float*)d_in[6];
    const float* b2           = (const float*)d_in[7];
    float* out = (float*)d_out;

    char* ws = (char*)d_ws;
    int*            idx  = (int*)(ws);                      // 393216 B
    float*          wgt  = (float*)(ws + 393216);           // 393216 B
    short*          W1b  = (short*)(ws + 786432);           // 196608 B
    short*          W2b  = (short*)(ws + 983040);           // 65536 B
    float*          kpk8 = (float*)(ws + 1048576);          // 131072 B
    unsigned short* KT16 = (unsigned short*)(ws + 1179648); // 4194304 B

    kpk_prep_kernel<<<8, 1024, 0, stream>>>(known, kpk8);

    knn_aux_kernel<<<2656, 1024, 0, stream>>>(
        unknown, kpk8, idx, wgt, known_feats, KT16, W1, W2, W1b, W2b);

    fp_mlp_mfma_kernel<<<BB * NN / (PT * TILES), 256, 0, stream>>>(
        unknow_feats, KT16, W1b, b1, W2b, b2, idx, wgt, out);
}

// Round 10
// 162.463 us; speedup vs baseline: 1.2435x; 1.0332x over previous
//
#include <hip/hip_runtime.h>
#include <hip/hip_bf16.h>

// PointNet2 FP: fused 3-NN + interp + concat + MLP(384->256->128), bf16 MFMA
#define BB 2
#define NN 16384
#define MM 4096
#define C1 128
#define C2 256
#define CIN 384
#define H1 256
#define H2 128
#define XROW 392       // 384 + 8 pad
#define HROW 264       // 256 + 8 pad

typedef __attribute__((ext_vector_type(8))) short bf16x8;
typedef __attribute__((ext_vector_type(4))) float f32x4;
typedef __attribute__((ext_vector_type(2))) float f32x2;
typedef __attribute__((ext_vector_type(8))) float f32x8;

__device__ __forceinline__ short f32_to_bf16(float x) {
    unsigned u = __float_as_uint(x);
    u += 0x7fffu + ((u >> 16) & 1u);   // RNE
    return (short)(u >> 16);
}
__device__ __forceinline__ float bf16_to_f32(unsigned short u) {
    union { unsigned u; float f; } c; c.u = ((unsigned)u) << 16; return c.f;
}
__device__ __forceinline__ unsigned pack_bf16x2(float a, float b) {
    __hip_bfloat162 h = __float22bfloat162_rn(make_float2(a, b));
    union { __hip_bfloat162 h; unsigned u; } cv;
    cv.h = h;
    return cv.u;
}
// score pair: each op has exactly ONE sgpr-pair operand -> no s->v movs.
// MUST be used identically in pass A and pass B (bit-identical scores).
__device__ __forceinline__ f32x2 score2(f32x2 ax2, f32x2 ay2, f32x2 az2,
                                        f32x2 kx, f32x2 ky, f32x2 kz, f32x2 kn) {
    f32x2 t = ay2 * ky;
    t = __builtin_elementwise_fma(ax2, kx, t);
    t = __builtin_elementwise_fma(az2, kz, t);
    return t + kn;
}

// ---------------- Kernel 1: prep — transpose + weight cast + kpk ---------
// blocks 0..2047: transpose KF (B,C2,M) -> KT16 (B,M,C2) bf16
// blocks 2048..2431: weight casts; 2432..2463: kpk pack. 256 thr.
__global__ __launch_bounds__(256) void prep_kernel(
    const float* __restrict__ KF, unsigned short* __restrict__ KT16,
    const float* __restrict__ W1, const float* __restrict__ W2,
    short* __restrict__ W1b, short* __restrict__ W2b,
    const float* __restrict__ known, float* __restrict__ kpk8)
{
    const int bx  = blockIdx.x;
    const int tid = threadIdx.x;
    if (bx < 2048) {
        __shared__ float tl[32][33];
        const int b  = bx >> 10;
        const int c0 = ((bx >> 7) & 7) * 32;
        const int m0 = (bx & 127) * 32;
        const int tx = tid & 31;
        const int ty = tid >> 5;            // 0..7
        #pragma unroll
        for (int r = 0; r < 4; ++r) {
            int c = ty + r * 8;
            tl[c][tx] = KF[((size_t)b * C2 + c0 + c) * MM + m0 + tx];
        }
        __syncthreads();
        #pragma unroll
        for (int r = 0; r < 4; ++r) {
            int m = ty + r * 8;
            KT16[((size_t)b * MM + m0 + m) * C2 + c0 + tx] =
                (unsigned short)f32_to_bf16(tl[tx][m]);
        }
    } else if (bx < 2432) {
        int i = (bx - 2048) * 256 + tid;
        if (i < H1 * CIN) W1b[i] = f32_to_bf16(W1[i]);
        if (i < H2 * H1)  W2b[i] = f32_to_bf16(W2[i]);
    } else {
        int i = (bx - 2432) * 256 + tid;
        if (i < BB * MM) {
            float x = known[3 * i + 0], y = known[3 * i + 1], z = known[3 * i + 2];
            float n = fmaf(x, x, fmaf(y, y, z * z));
            int g = i >> 1, j = i & 1;
            float* base = kpk8 + (size_t)g * 8;
            base[0 + j] = x; base[2 + j] = y; base[4 + j] = z; base[6 + j] = n;
        }
    }
}

// -------- Kernel 2: fused knn + gather-interp + 2-layer MFMA MLP ---------
// grid 512, block 1024 (16 waves). Block owns 64 queries: phase 1 = two-pass
// 3-NN (idx/wgt -> LDS, no global round-trip); phase 2 = MLP on its own 64
// points as 2 tiles of 32 (16-wave GEMM partition). Cross-block skew
// overlaps knn VALU with MLP MFMA/memory (m114 co-scheduling).
__global__ __launch_bounds__(1024, 8) void fused_knn_mlp_kernel(
    const float* __restrict__ unknown,        // (B,N,3)
    const float* __restrict__ kpk8,           // packed candidate groups
    const float* __restrict__ unknow_feats,   // (B,C1,N)
    const unsigned short* __restrict__ KT16,  // (B,M,C2) bf16
    const short* __restrict__ W1b, const float* __restrict__ b1,
    const short* __restrict__ W2b, const float* __restrict__ b2,
    float* __restrict__ out)                  // (B,H2,N)
{
    __shared__ float pdv[16][64][3];
    __shared__ float vf[64];
    __shared__ float msc[64][8];
    __shared__ int   mid[64][8];
    __shared__ int   cnt[64];
    __shared__ int   IsL[64 * 3];
    __shared__ float WsL[64 * 3];
    __shared__ short XH[32][XROW];
    __shared__ short Hs[32][HROW];

    const int bx    = blockIdx.x;             // 0..511
    const int tid   = threadIdx.x;
    const int lane  = tid & 63;
    const int w     = __builtin_amdgcn_readfirstlane(tid >> 6);  // 0..15
    const int b     = bx >> 8;
    const int qbase = (bx & 255) * 64;
    const int n     = qbase + lane;

    if (tid < 64) cnt[tid] = 0;

    // ================= Phase 1: 3-NN for this block's 64 queries =========
    {
        const float ux = unknown[((size_t)b * NN + n) * 3 + 0];
        const float uy = unknown[((size_t)b * NN + n) * 3 + 1];
        const float uz = unknown[((size_t)b * NN + n) * 3 + 2];
        const f32x2 ax2 = {-2.f * ux, -2.f * ux};
        const f32x2 ay2 = {-2.f * uy, -2.f * uy};
        const f32x2 az2 = {-2.f * uz, -2.f * uz};
        const float un = fmaf(ux, ux, fmaf(uy, uy, uz * uz));

        const int gbase = w * 128;
        const float* __restrict__ kp = kpk8 + ((size_t)b * (MM / 2) + gbase) * 8;

        // Pass A: values-only top-3, dual accumulators
        float va0 = 3e38f, va1 = 3e38f, va2 = 3e38f;
        float vb0 = 3e38f, vb1 = 3e38f, vb2 = 3e38f;
        #pragma unroll 4
        for (int g = 0; g < 128; ++g) {
            const f32x8 G = *(const f32x8*)(kp + (size_t)g * 8);   // uniform
            const f32x2 kx = __builtin_shufflevector(G, G, 0, 1);
            const f32x2 ky = __builtin_shufflevector(G, G, 2, 3);
            const f32x2 kz = __builtin_shufflevector(G, G, 4, 5);
            const f32x2 kn = __builtin_shufflevector(G, G, 6, 7);
            const f32x2 sc2 = score2(ax2, ay2, az2, kx, ky, kz, kn);
            float sa = sc2.x;
            va2 = __builtin_amdgcn_fmed3f(va1, sa, va2);
            va1 = __builtin_amdgcn_fmed3f(va0, sa, va1);
            va0 = fminf(sa, va0);
            float sb = sc2.y;
            vb2 = __builtin_amdgcn_fmed3f(vb1, sb, vb2);
            vb1 = __builtin_amdgcn_fmed3f(vb0, sb, vb1);
            vb0 = fminf(sb, vb0);
        }
        {
            float bv[3] = {vb0, vb1, vb2};
            #pragma unroll
            for (int k = 0; k < 3; ++k) {
                float d = bv[k];
                va2 = __builtin_amdgcn_fmed3f(va1, d, va2);
                va1 = __builtin_amdgcn_fmed3f(va0, d, va1);
                va0 = fminf(d, va0);
            }
        }
        pdv[w][lane][0] = va0; pdv[w][lane][1] = va1; pdv[w][lane][2] = va2;
        __syncthreads();

        if (tid < 64) {
            float r0 = 3e38f, r1 = 3e38f, r2 = 3e38f;
            #pragma unroll
            for (int ww = 0; ww < 16; ++ww) {
                #pragma unroll
                for (int k = 0; k < 3; ++k) {
                    float d = pdv[ww][tid][k];
                    r2 = __builtin_amdgcn_fmed3f(r1, d, r2);
                    r1 = __builtin_amdgcn_fmed3f(r0, d, r1);
                    r0 = fminf(d, r0);
                }
            }
            vf[tid] = r2;
        }
        __syncthreads();

        // Pass B: index recovery — identical score arithmetic
        const float v2f = vf[lane];
        #pragma unroll 4
        for (int g = 0; g < 128; ++g) {
            const f32x8 G = *(const f32x8*)(kp + (size_t)g * 8);
            const f32x2 kx = __builtin_shufflevector(G, G, 0, 1);
            const f32x2 ky = __builtin_shufflevector(G, G, 2, 3);
            const f32x2 kz = __builtin_shufflevector(G, G, 4, 5);
            const f32x2 kn = __builtin_shufflevector(G, G, 6, 7);
            const f32x2 sc2 = score2(ax2, ay2, az2, kx, ky, kz, kn);
            if (fminf(sc2.x, sc2.y) <= v2f) {
                if (sc2.x <= v2f) {
                    int c = atomicAdd(&cnt[lane], 1);
                    if (c < 8) { msc[lane][c] = sc2.x; mid[lane][c] = (gbase + g) * 2; }
                }
                if (sc2.y <= v2f) {
                    int c = atomicAdd(&cnt[lane], 1);
                    if (c < 8) { msc[lane][c] = sc2.y; mid[lane][c] = (gbase + g) * 2 + 1; }
                }
            }
        }
        __syncthreads();

        if (tid < 64) {
            const int c = cnt[tid] < 8 ? cnt[tid] : 8;
            float r0 = 3e38f, r1 = 3e38f, r2 = 3e38f;
            int   q0 = 0x7FFFFFFF, q1 = 0x7FFFFFFF, q2 = 0x7FFFFFFF;
            #pragma unroll
            for (int k = 0; k < 8; ++k) {
                float d = (k < c) ? msc[tid][k] : 3e38f;
                int   j = (k < c) ? mid[tid][k] : 0x7FFFFFFF;
                const bool lt0 = (d < r0) || (d == r0 && j < q0);
                const bool lt1 = (d < r1) || (d == r1 && j < q1);
                const bool lt2 = (d < r2) || (d == r2 && j < q2);
                float nr2 = lt1 ? r1 : (lt2 ? d : r2);
                int   nq2 = lt1 ? q1 : (lt2 ? j : q2);
                float nr1 = lt0 ? r0 : (lt1 ? d : r1);
                int   nq1 = lt0 ? q0 : (lt1 ? j : q1);
                float nr0 = lt0 ? d : r0;
                int   nq0 = lt0 ? j : q0;
                r0 = nr0; r1 = nr1; r2 = nr2; q0 = nq0; q1 = nq1; q2 = nq2;
            }
            float d0 = sqrtf(fmaxf(r0 + un, 0.f));
            float d1 = sqrtf(fmaxf(r1 + un, 0.f));
            float d2 = sqrtf(fmaxf(r2 + un, 0.f));
            float i0 = 1.f / (d0 + 1e-8f);
            float i1 = 1.f / (d1 + 1e-8f);
            float i2 = 1.f / (d2 + 1e-8f);
            float s  = i0 + i1 + i2;
            IsL[tid * 3 + 0] = q0; IsL[tid * 3 + 1] = q1; IsL[tid * 3 + 2] = q2;
            WsL[tid * 3 + 0] = i0 / s; WsL[tid * 3 + 1] = i1 / s; WsL[tid * 3 + 2] = i2 / s;
        }
    }
    __syncthreads();

    // ================= Phase 2: MLP on this block's 64 points ============
    const unsigned short* KTb = KT16 + (size_t)b * MM * C2;
    const int lr = lane & 15;
    const int lq = lane >> 4;
    const int c4 = lane << 2;                    // 0..252

    for (int tile = 0; tile < 2; ++tile) {
        const int pbase = tile * 32;

        // ---- X build: wave w -> local points 2w, 2w+1 (issue all 6 gathers)
        {
            ushort4 g[2][3];
            #pragma unroll
            for (int j = 0; j < 2; ++j) {
                const int pi = (pbase + 2 * w + j) * 3;
                g[j][0] = *(const ushort4*)(KTb + (size_t)IsL[pi + 0] * C2 + c4);
                g[j][1] = *(const ushort4*)(KTb + (size_t)IsL[pi + 1] * C2 + c4);
                g[j][2] = *(const ushort4*)(KTb + (size_t)IsL[pi + 2] * C2 + c4);
            }
            #pragma unroll
            for (int j = 0; j < 2; ++j) {
                const int pl = 2 * w + j;
                const int pi = (pbase + pl) * 3;
                const float w0 = WsL[pi + 0], w1 = WsL[pi + 1], w2 = WsL[pi + 2];
                float vx = fmaf(w0, bf16_to_f32(g[j][0].x), fmaf(w1, bf16_to_f32(g[j][1].x), w2 * bf16_to_f32(g[j][2].x)));
                float vy = fmaf(w0, bf16_to_f32(g[j][0].y), fmaf(w1, bf16_to_f32(g[j][1].y), w2 * bf16_to_f32(g[j][2].y)));
                float vz = fmaf(w0, bf16_to_f32(g[j][0].z), fmaf(w1, bf16_to_f32(g[j][1].z), w2 * bf16_to_f32(g[j][2].z)));
                float vw = fmaf(w0, bf16_to_f32(g[j][0].w), fmaf(w1, bf16_to_f32(g[j][1].w), w2 * bf16_to_f32(g[j][2].w)));
                uint2 pk;
                pk.x = pack_bf16x2(vx, vy);
                pk.y = pack_bf16x2(vz, vw);
                *(uint2*)&XH[pl][c4] = pk;
            }
            const float* UFb = unknow_feats + (size_t)b * C1 * NN + qbase + pbase;
            const int cc = tid >> 3;              // 0..127
            const int nq = (tid & 7) << 2;        // 0,4,..,28
            const float4 f = *(const float4*)(UFb + (size_t)cc * NN + nq);
            XH[nq + 0][C2 + cc] = f32_to_bf16(f.x);
            XH[nq + 1][C2 + cc] = f32_to_bf16(f.y);
            XH[nq + 2][C2 + cc] = f32_to_bf16(f.z);
            XH[nq + 3][C2 + cc] = f32_to_bf16(f.w);
        }
        __syncthreads();

        // ---- GEMM1: wave w -> H1 rows [16w, 16w+16), 32 points ----
        f32x4 acc1[2];
        acc1[0] = (f32x4){0.f, 0.f, 0.f, 0.f};
        acc1[1] = (f32x4){0.f, 0.f, 0.f, 0.f};
        #pragma unroll 4
        for (int k0 = 0; k0 < CIN; k0 += 32) {
            bf16x8 a  = *(const bf16x8*)(W1b + (size_t)(w * 16 + lr) * CIN + k0 + lq * 8);
            bf16x8 x0 = *(bf16x8*)&XH[lr][k0 + lq * 8];
            bf16x8 x1 = *(bf16x8*)&XH[16 + lr][k0 + lq * 8];
            acc1[0] = __builtin_amdgcn_mfma_f32_16x16x32_bf16(a, x0, acc1[0], 0, 0, 0);
            acc1[1] = __builtin_amdgcn_mfma_f32_16x16x32_bf16(a, x1, acc1[1], 0, 0, 0);
        }
        {
            const int ob = w * 16 + lq * 4;
            float bb0 = b1[ob + 0], bb1 = b1[ob + 1], bb2 = b1[ob + 2], bb3 = b1[ob + 3];
            #pragma unroll
            for (int p = 0; p < 2; ++p) {
                uint2 pk;
                pk.x = pack_bf16x2(fmaxf(acc1[p].x + bb0, 0.f),
                                   fmaxf(acc1[p].y + bb1, 0.f));
                pk.y = pack_bf16x2(fmaxf(acc1[p].z + bb2, 0.f),
                                   fmaxf(acc1[p].w + bb3, 0.f));
                *(uint2*)&Hs[p * 16 + lr][ob] = pk;
            }
        }
        __syncthreads();

        // ---- GEMM2: wave w -> H2 rows [16(w&7),+16), points [16(w>>3),+16)
        {
            const int r0 = (w & 7) * 16;
            const int pg = (w >> 3) * 16;
            f32x4 acc2 = (f32x4){0.f, 0.f, 0.f, 0.f};
            #pragma unroll 4
            for (int k0 = 0; k0 < H1; k0 += 32) {
                bf16x8 a2 = *(const bf16x8*)(W2b + (size_t)(r0 + lr) * H1 + k0 + lq * 8);
                bf16x8 h  = *(bf16x8*)&Hs[pg + lr][k0 + lq * 8];
                acc2 = __builtin_amdgcn_mfma_f32_16x16x32_bf16(a2, h, acc2, 0, 0, 0);
            }
            const int nn = qbase + pbase + pg + lr;
            #pragma unroll
            for (int r = 0; r < 4; ++r) {
                const int o = r0 + lq * 4 + r;
                out[((size_t)b * H2 + o) * NN + nn] =
                    fmaxf(((const float*)&acc2)[r] + b2[o], 0.f);
            }
        }
        __syncthreads();   // Hs/XH free for next tile
    }
}

extern "C" void kernel_launch(void* const* d_in, const int* in_sizes, int n_in,
                              void* d_out, int out_size, void* d_ws, size_t ws_size,
                              hipStream_t stream) {
    const float* unknown      = (const float*)d_in[0];
    const float* known        = (const float*)d_in[1];
    const float* unknow_feats = (const float*)d_in[2];
    const float* known_feats  = (const float*)d_in[3];
    const float* W1           = (const float*)d_in[4];
    const float* b1           = (const float*)d_in[5];
    const float* W2           = (const float*)d_in[6];
    const float* b2           = (const float*)d_in[7];
    float* out = (float*)d_out;

    char* ws = (char*)d_ws;
    short*          W1b  = (short*)(ws);                    // 196608 B
    short*          W2b  = (short*)(ws + 196608);           // 65536 B
    float*          kpk8 = (float*)(ws + 262144);           // 131072 B
    unsigned short* KT16 = (unsigned short*)(ws + 393216);  // 4194304 B

    prep_kernel<<<2464, 256, 0, stream>>>(
        known_feats, KT16, W1, W2, W1b, W2b, known, kpk8);

    fused_knn_mlp_kernel<<<512, 1024, 0, stream>>>(
        unknown, kpk8, unknow_feats, KT16, W1b, b1, W2b, b2, out);
}